// Round 1
// baseline (1345.015 us; speedup 1.0000x reference)
//
#include <hip/hip_runtime.h>

#define NNODES 64000
#define NGRAPHS 128
#define D 64

__device__ __forceinline__ float bcastf(float v, int l) {
    return __uint_as_float(__builtin_amdgcn_readlane(__float_as_uint(v), l));
}

// cnt[i] = in-degree of node i (dst side)
__global__ void degree_kernel(const int* __restrict__ dst, int E, int* __restrict__ cnt) {
    int i = blockIdx.x * blockDim.x + threadIdx.x;
    int stride = gridDim.x * blockDim.x;
    for (int e = i; e < E; e += stride) atomicAdd(&cnt[dst[e]], 1);
}

__global__ void inv_kernel(const int* __restrict__ cnt, float* __restrict__ inv, int N) {
    int i = blockIdx.x * blockDim.x + threadIdx.x;
    if (i < N) inv[i] = cnt[i] > 0 ? 1.0f / (float)cnt[i] : 0.0f;
}

// s[dst] += h[src], one wave per edge, lane = feature index
__global__ void scatter_kernel(const float* __restrict__ h, float* __restrict__ s,
                               const int* __restrict__ src, const int* __restrict__ dst, int E) {
    int lane = threadIdx.x & 63;
    int wid  = (blockIdx.x * blockDim.x + threadIdx.x) >> 6;
    int nw   = (gridDim.x * blockDim.x) >> 6;
    for (int e = wid; e < E; e += nw) {
        int sN = src[e];
        int dN = dst[e];
        float v = h[(size_t)sN * D + lane];
        atomicAdd(&s[(size_t)dN * D + lane], v);
    }
}

// out[i][j] = b[j] + sum_k aggr[i][k]*Wl[j][k] + sum_k h[i][k]*Wr[j][k]
// aggr = s * inv (in-place into s). One wave per node; lane j holds W rows in VGPRs.
template <int RELU>
__global__ __launch_bounds__(256) void transform_kernel(
        float* __restrict__ s, const float* __restrict__ h, const float* __restrict__ inv,
        const float* __restrict__ Wl, const float* __restrict__ Wr,
        const float* __restrict__ b, int N) {
    int lane = threadIdx.x & 63;
    int wid  = (blockIdx.x * blockDim.x + threadIdx.x) >> 6;
    int nw   = (gridDim.x * blockDim.x) >> 6;

    float wl[D], wr[D];
    const float4* Wl4 = (const float4*)(Wl + lane * D);
    const float4* Wr4 = (const float4*)(Wr + lane * D);
#pragma unroll
    for (int k4 = 0; k4 < D / 4; ++k4) {
        float4 a = Wl4[k4];
        wl[4*k4] = a.x; wl[4*k4+1] = a.y; wl[4*k4+2] = a.z; wl[4*k4+3] = a.w;
        float4 c = Wr4[k4];
        wr[4*k4] = c.x; wr[4*k4+1] = c.y; wr[4*k4+2] = c.z; wr[4*k4+3] = c.w;
    }
    float bv = b[lane];

    for (int i = wid; i < N; i += nw) {
        float iv = inv[i];
        float aj = s[(size_t)i * D + lane] * iv;
        float hj = h[(size_t)i * D + lane];
        float a0 = 0.f, a1 = 0.f, a2 = 0.f, a3 = 0.f;
#pragma unroll
        for (int k = 0; k < D; k += 2) {
            a0 = fmaf(bcastf(aj, k),     wl[k],     a0);
            a1 = fmaf(bcastf(hj, k),     wr[k],     a1);
            a2 = fmaf(bcastf(aj, k + 1), wl[k + 1], a2);
            a3 = fmaf(bcastf(hj, k + 1), wr[k + 1], a3);
        }
        float acc = bv + (a0 + a2) + (a1 + a3);
        if (RELU) acc = fmaxf(acc, 0.0f);
        s[(size_t)i * D + lane] = acc;
    }
}

// final SAGE layer (out dim 2) fused with global mean-pool accumulation
__global__ void final_pool_kernel(const float* __restrict__ sF, const float* __restrict__ h,
                                  const float* __restrict__ inv, const int* __restrict__ batch,
                                  const float* __restrict__ Wlo, const float* __restrict__ Wro,
                                  const float* __restrict__ bo, float* __restrict__ pool, int N) {
    __shared__ float WloS[2 * D], WroS[2 * D], boS[2];
    int t = threadIdx.x;
    if (t < 2 * D) { WloS[t] = Wlo[t]; WroS[t] = Wro[t]; }
    if (t < 2) boS[t] = bo[t];
    __syncthreads();

    int i0 = blockIdx.x * blockDim.x + t;
    int stride = gridDim.x * blockDim.x;
    for (int i = i0; i < N; i += stride) {
        float iv = inv[i];
        const float4* a4 = (const float4*)(sF + (size_t)i * D);
        const float4* h4 = (const float4*)(h + (size_t)i * D);
        float o0 = boS[0], o1 = boS[1];
#pragma unroll
        for (int k4 = 0; k4 < D / 4; ++k4) {
            float4 av = a4[k4], hv = h4[k4];
            int k = 4 * k4;
            float ax = av.x * iv, ay = av.y * iv, az = av.z * iv, aw = av.w * iv;
            o0 += ax * WloS[k] + ay * WloS[k+1] + az * WloS[k+2] + aw * WloS[k+3]
                + hv.x * WroS[k] + hv.y * WroS[k+1] + hv.z * WroS[k+2] + hv.w * WroS[k+3];
            o1 += ax * WloS[D+k] + ay * WloS[D+k+1] + az * WloS[D+k+2] + aw * WloS[D+k+3]
                + hv.x * WroS[D+k] + hv.y * WroS[D+k+1] + hv.z * WroS[D+k+2] + hv.w * WroS[D+k+3];
        }
        int g = batch[i];
        atomicAdd(&pool[g * 2 + 0], o0);
        atomicAdd(&pool[g * 2 + 1], o1);
        atomicAdd(&pool[2 * NGRAPHS + g], 1.0f);
    }
}

__global__ void writeout_kernel(const float* __restrict__ pool, float* __restrict__ out) {
    int t = blockIdx.x * blockDim.x + threadIdx.x;
    if (t < 2 * NGRAPHS) {
        int g = t >> 1;
        float c = pool[2 * NGRAPHS + g];
        out[t] = pool[t] / fmaxf(c, 1.0f);
    }
}

extern "C" void kernel_launch(void* const* d_in, const int* in_sizes, int n_in,
                              void* d_out, int out_size, void* d_ws, size_t ws_size,
                              hipStream_t stream) {
    const float* x    = (const float*)d_in[0];
    const int*   eidx = (const int*)d_in[1];
    const int*   batch= (const int*)d_in[2];
    const float* Wl   = (const float*)d_in[3];
    const float* Wr   = (const float*)d_in[4];
    const float* b    = (const float*)d_in[5];
    const float* Wlo  = (const float*)d_in[6];
    const float* Wro  = (const float*)d_in[7];
    const float* bo   = (const float*)d_in[8];

    int E = in_sizes[1] / 2;
    const int* src = eidx;
    const int* dst = eidx + E;

    char* ws = (char*)d_ws;
    size_t hb = (size_t)NNODES * D * sizeof(float);  // 16,384,000 bytes
    float* bufA = (float*)ws;
    float* bufB = (float*)(ws + hb);
    float* invp = (float*)(ws + 2 * hb);
    int*   cnt  = (int*)(ws + 2 * hb + NNODES * sizeof(float));
    float* pool = (float*)(ws + 2 * hb + 2 * (size_t)NNODES * sizeof(float));

    hipMemsetAsync(cnt, 0, NNODES * sizeof(int), stream);
    hipMemsetAsync(pool, 0, 3 * NGRAPHS * sizeof(float), stream);
    degree_kernel<<<1024, 256, 0, stream>>>(dst, E, cnt);
    inv_kernel<<<(NNODES + 255) / 256, 256, 0, stream>>>(cnt, invp, NNODES);

    float* bufs[2] = {bufA, bufB};
    const float* hcur = x;
    int cur = 0;
    for (int l = 0; l < 3; ++l) {
        float* sb = bufs[cur];
        hipMemsetAsync(sb, 0, hb, stream);
        scatter_kernel<<<4096, 256, 0, stream>>>(hcur, sb, src, dst, E);
        transform_kernel<1><<<2048, 256, 0, stream>>>(sb, hcur, invp,
                                                      Wl + l * D * D, Wr + l * D * D,
                                                      b + l * D, NNODES);
        hcur = sb;
        cur ^= 1;
    }

    float* sF = bufs[cur];
    hipMemsetAsync(sF, 0, hb, stream);
    scatter_kernel<<<4096, 256, 0, stream>>>(hcur, sF, src, dst, E);
    final_pool_kernel<<<256, 256, 0, stream>>>(sF, hcur, invp, batch, Wlo, Wro, bo,
                                               pool, NNODES);
    writeout_kernel<<<1, 256, 0, stream>>>(pool, (float*)d_out);
}

// Round 2
// 595.898 us; speedup vs baseline: 2.2571x; 2.2571x over previous
//
#include <hip/hip_runtime.h>

#define NNODES 64000
#define NGRAPHS 128
#define D 64

__device__ __forceinline__ float bcastf(float v, int l) {
    return __uint_as_float(__builtin_amdgcn_readlane(__float_as_uint(v), l));
}

__device__ __forceinline__ int lower_bound(const int* __restrict__ a, int n, int key) {
    int lo = 0, hi = n;
    while (lo < hi) {
        int mid = (lo + hi) >> 1;
        if (a[mid] < key) lo = mid + 1; else hi = mid;
    }
    return lo;
}

// ---- CSR build -------------------------------------------------------------

__global__ void degree_kernel(const int* __restrict__ dst, int E, int* __restrict__ cnt) {
    int i = blockIdx.x * blockDim.x + threadIdx.x;
    int stride = gridDim.x * blockDim.x;
    for (int e = i; e < E; e += stride) atomicAdd(&cnt[dst[e]], 1);
}

// per-block sums of cnt (250 blocks x 256)
__global__ void blocksum_kernel(const int* __restrict__ cnt, int* __restrict__ bsum) {
    __shared__ int s[256];
    int t = threadIdx.x;
    s[t] = cnt[blockIdx.x * 256 + t];
    __syncthreads();
    for (int off = 128; off > 0; off >>= 1) {
        if (t < off) s[t] += s[t + off];
        __syncthreads();
    }
    if (t == 0) bsum[blockIdx.x] = s[0];
}

// exclusive scan of bsum[nb] (single block, 256 threads, Hillis-Steele)
__global__ void scansmall_kernel(int* __restrict__ bsum, int nb) {
    __shared__ int s[256];
    int t = threadIdx.x;
    int v = (t < nb) ? bsum[t] : 0;
    s[t] = v;
    __syncthreads();
    for (int off = 1; off < 256; off <<= 1) {
        int x = (t >= off) ? s[t - off] : 0;
        __syncthreads();
        s[t] += x;
        __syncthreads();
    }
    if (t < nb) bsum[t] = s[t] - v;   // exclusive
}

// per-block exclusive scan + base -> offs, cur; writes offs[N] at the end
__global__ void scanfinal_kernel(const int* __restrict__ cnt, const int* __restrict__ bsum,
                                 int* __restrict__ offs, int* __restrict__ cur, int N) {
    __shared__ int s[256];
    int t = threadIdx.x;
    int i = blockIdx.x * 256 + t;
    int v = cnt[i];
    s[t] = v;
    __syncthreads();
    for (int off = 1; off < 256; off <<= 1) {
        int x = (t >= off) ? s[t - off] : 0;
        __syncthreads();
        s[t] += x;
        __syncthreads();
    }
    int incl = s[t];
    int base = bsum[blockIdx.x];
    int o = base + incl - v;
    offs[i] = o;
    cur[i] = o;
    if (i == N - 1) offs[N] = base + incl;
}

__global__ void fill_kernel(const int* __restrict__ src, const int* __restrict__ dst,
                            int* __restrict__ cur, int* __restrict__ col, int E) {
    int i = blockIdx.x * blockDim.x + threadIdx.x;
    int stride = gridDim.x * blockDim.x;
    for (int e = i; e < E; e += stride) {
        int d = dst[e];
        int p = atomicAdd(&cur[d], 1);
        col[p] = src[e];
    }
}

// ---- fused SAGE layer: gather-mean + GEMV + bias + relu --------------------
// one wave per node; lane j holds Wl[j,:], Wr[j,:] in VGPRs
template <int RELU>
__global__ __launch_bounds__(256) void fused_layer_kernel(
        const float* __restrict__ h, float* __restrict__ out,
        const int* __restrict__ offs, const int* __restrict__ col,
        const float* __restrict__ Wl, const float* __restrict__ Wr,
        const float* __restrict__ b, int N) {
    int lane = threadIdx.x & 63;
    int wid  = (blockIdx.x * blockDim.x + threadIdx.x) >> 6;
    int nw   = (gridDim.x * blockDim.x) >> 6;

    float wl[D], wr[D];
    const float4* Wl4 = (const float4*)(Wl + lane * D);
    const float4* Wr4 = (const float4*)(Wr + lane * D);
#pragma unroll
    for (int k4 = 0; k4 < D / 4; ++k4) {
        float4 a = Wl4[k4];
        wl[4*k4] = a.x; wl[4*k4+1] = a.y; wl[4*k4+2] = a.z; wl[4*k4+3] = a.w;
        float4 c = Wr4[k4];
        wr[4*k4] = c.x; wr[4*k4+1] = c.y; wr[4*k4+2] = c.z; wr[4*k4+3] = c.w;
    }
    float bv = b[lane];

    for (int i = wid; i < N; i += nw) {
        int beg = offs[i], end = offs[i + 1];
        float acc0 = 0.f, acc1 = 0.f;
        int e = beg;
        for (; e + 4 <= end; e += 4) {
            int c0 = col[e], c1 = col[e+1], c2 = col[e+2], c3 = col[e+3];
            float v0 = h[(size_t)c0 * D + lane];
            float v1 = h[(size_t)c1 * D + lane];
            float v2 = h[(size_t)c2 * D + lane];
            float v3 = h[(size_t)c3 * D + lane];
            acc0 += v0 + v2;
            acc1 += v1 + v3;
        }
        for (; e < end; ++e) acc0 += h[(size_t)col[e] * D + lane];
        int deg = end - beg;
        float aj = (deg > 0) ? (acc0 + acc1) / (float)deg : 0.f;
        float hj = h[(size_t)i * D + lane];

        float a0 = 0.f, a1 = 0.f, a2 = 0.f, a3 = 0.f;
#pragma unroll
        for (int k = 0; k < D; k += 2) {
            a0 = fmaf(bcastf(aj, k),     wl[k],     a0);
            a1 = fmaf(bcastf(hj, k),     wr[k],     a1);
            a2 = fmaf(bcastf(aj, k + 1), wl[k + 1], a2);
            a3 = fmaf(bcastf(hj, k + 1), wr[k + 1], a3);
        }
        float acc = bv + (a0 + a2) + (a1 + a3);
        if (RELU) acc = fmaxf(acc, 0.0f);
        out[(size_t)i * D + lane] = acc;
    }
}

// ---- final layer: per-graph sums of aggr and h (linearity of out transform)
// grid = NGRAPHS * BPG blocks; batch sorted -> binary search graph range
#define BPG 8
__global__ __launch_bounds__(256) void graph_sums_kernel(
        const float* __restrict__ h, const int* __restrict__ offs,
        const int* __restrict__ col, const int* __restrict__ batch,
        float* __restrict__ SA, float* __restrict__ SH, int* __restrict__ gcnt) {
    int g    = blockIdx.x / BPG;
    int part = blockIdx.x % BPG;
    int lane = threadIdx.x & 63;
    int w    = threadIdx.x >> 6;          // 4 waves
    int start = lower_bound(batch, NNODES, g);
    int end   = lower_bound(batch, NNODES, g + 1);

    float sa = 0.f, sh = 0.f;
    for (int i = start + part * 4 + w; i < end; i += BPG * 4) {
        int beg = offs[i], e2 = offs[i + 1];
        float acc0 = 0.f, acc1 = 0.f;
        int e = beg;
        for (; e + 4 <= e2; e += 4) {
            int c0 = col[e], c1 = col[e+1], c2 = col[e+2], c3 = col[e+3];
            float v0 = h[(size_t)c0 * D + lane];
            float v1 = h[(size_t)c1 * D + lane];
            float v2 = h[(size_t)c2 * D + lane];
            float v3 = h[(size_t)c3 * D + lane];
            acc0 += v0 + v2;
            acc1 += v1 + v3;
        }
        for (; e < e2; ++e) acc0 += h[(size_t)col[e] * D + lane];
        int deg = e2 - beg;
        sa += (deg > 0) ? (acc0 + acc1) / (float)deg : 0.f;
        sh += h[(size_t)i * D + lane];
    }

    __shared__ float redA[4][D], redH[4][D];
    redA[w][lane] = sa;
    redH[w][lane] = sh;
    __syncthreads();
    if (w == 0) {
        float A = redA[0][lane] + redA[1][lane] + redA[2][lane] + redA[3][lane];
        float H = redH[0][lane] + redH[1][lane] + redH[2][lane] + redH[3][lane];
        atomicAdd(&SA[g * D + lane], A);
        atomicAdd(&SH[g * D + lane], H);
        if (lane == 0 && part == 0) gcnt[g] = end - start;
    }
}

// out[g][j] = (SA[g]·Wlo[j] + SH[g]·Wro[j]) / cnt + bo[j]   (0 if cnt==0)
__global__ void out_kernel(const float* __restrict__ SA, const float* __restrict__ SH,
                           const int* __restrict__ gcnt,
                           const float* __restrict__ Wlo, const float* __restrict__ Wro,
                           const float* __restrict__ bo, float* __restrict__ out) {
    int t = threadIdx.x;             // 256 = 128 graphs x 2 classes
    int g = t >> 1, j = t & 1;
    float acc = 0.f;
#pragma unroll
    for (int k = 0; k < D; ++k)
        acc += SA[g * D + k] * Wlo[j * D + k] + SH[g * D + k] * Wro[j * D + k];
    int c = gcnt[g];
    out[t] = (c > 0) ? acc / (float)c + bo[j] : 0.f;
}

// ---- launch ---------------------------------------------------------------

extern "C" void kernel_launch(void* const* d_in, const int* in_sizes, int n_in,
                              void* d_out, int out_size, void* d_ws, size_t ws_size,
                              hipStream_t stream) {
    const float* x    = (const float*)d_in[0];
    const int*   eidx = (const int*)d_in[1];
    const int*   batch= (const int*)d_in[2];
    const float* Wl   = (const float*)d_in[3];
    const float* Wr   = (const float*)d_in[4];
    const float* b    = (const float*)d_in[5];
    const float* Wlo  = (const float*)d_in[6];
    const float* Wro  = (const float*)d_in[7];
    const float* bo   = (const float*)d_in[8];

    int E = in_sizes[1] / 2;
    const int* src = eidx;
    const int* dst = eidx + E;

    char* ws = (char*)d_ws;
    size_t hb = (size_t)NNODES * D * sizeof(float);          // 16,384,000
    float* bufA = (float*)ws;
    float* bufB = (float*)(ws + hb);
    int*   col  = (int*)(ws + 2 * hb);                       // E ints
    char*  p    = ws + 2 * hb + (size_t)E * 4;
    int*   offs = (int*)p;            p += ((size_t)(NNODES + 1) * 4 + 15) / 16 * 16;
    int*   cur  = (int*)p;            p += (size_t)NNODES * 4;
    int*   cnt  = (int*)p;            p += (size_t)NNODES * 4;
    int*   bsum = (int*)p;            p += 1024;
    float* SA   = (float*)p;          p += (size_t)NGRAPHS * D * 4;
    float* SH   = (float*)p;          p += (size_t)NGRAPHS * D * 4;
    int*   gcnt = (int*)p;

    const int NB = NNODES / 256;      // 250

    hipMemsetAsync(cnt, 0, (size_t)NNODES * 4, stream);
    hipMemsetAsync(SA, 0, 2 * (size_t)NGRAPHS * D * 4 + 512, stream);  // SA, SH, gcnt

    degree_kernel<<<1024, 256, 0, stream>>>(dst, E, cnt);
    blocksum_kernel<<<NB, 256, 0, stream>>>(cnt, bsum);
    scansmall_kernel<<<1, 256, 0, stream>>>(bsum, NB);
    scanfinal_kernel<<<NB, 256, 0, stream>>>(cnt, bsum, offs, cur, NNODES);
    fill_kernel<<<2048, 256, 0, stream>>>(src, dst, cur, col, E);

    fused_layer_kernel<1><<<2048, 256, 0, stream>>>(x,    bufA, offs, col,
                                                    Wl + 0 * D * D, Wr + 0 * D * D, b + 0 * D, NNODES);
    fused_layer_kernel<1><<<2048, 256, 0, stream>>>(bufA, bufB, offs, col,
                                                    Wl + 1 * D * D, Wr + 1 * D * D, b + 1 * D, NNODES);
    fused_layer_kernel<1><<<2048, 256, 0, stream>>>(bufB, bufA, offs, col,
                                                    Wl + 2 * D * D, Wr + 2 * D * D, b + 2 * D, NNODES);

    graph_sums_kernel<<<NGRAPHS * BPG, 256, 0, stream>>>(bufA, offs, col, batch,
                                                         SA, SH, gcnt);
    out_kernel<<<1, 256, 0, stream>>>(SA, SH, gcnt, Wlo, Wro, bo, (float*)d_out);
}

// Round 3
// 460.566 us; speedup vs baseline: 2.9204x; 1.2938x over previous
//
#include <hip/hip_runtime.h>

#define NNODES 64000
#define NGRAPHS 128
#define D 64
#define NPW 8   // nodes per wave group in fused layer

__device__ __forceinline__ float bf2f(unsigned short u) {
    return __uint_as_float(((unsigned int)u) << 16);
}
__device__ __forceinline__ unsigned short f2bf(float f) {
    unsigned int u = __float_as_uint(f);
    unsigned int r = (u + 0x7fffu + ((u >> 16) & 1u)) >> 16;   // RNE
    return (unsigned short)r;
}
__device__ __forceinline__ float bcastf(float v, int l) {
    return __uint_as_float(__builtin_amdgcn_readlane(__float_as_uint(v), l));
}

__device__ __forceinline__ int lower_bound(const int* __restrict__ a, int n, int key) {
    int lo = 0, hi = n;
    while (lo < hi) {
        int mid = (lo + hi) >> 1;
        if (a[mid] < key) lo = mid + 1; else hi = mid;
    }
    return lo;
}

// ---- bf16 conversion of x --------------------------------------------------

__global__ void tobf_kernel(const float4* __restrict__ x, ushort4* __restrict__ xb, int n4) {
    int i = blockIdx.x * blockDim.x + threadIdx.x;
    int st = gridDim.x * blockDim.x;
    for (; i < n4; i += st) {
        float4 v = x[i];
        ushort4 o;
        o.x = f2bf(v.x); o.y = f2bf(v.y); o.z = f2bf(v.z); o.w = f2bf(v.w);
        xb[i] = o;
    }
}

// ---- CSR build -------------------------------------------------------------

__global__ void degree_kernel(const int* __restrict__ dst, int E, int* __restrict__ cnt) {
    int i = blockIdx.x * blockDim.x + threadIdx.x;
    int stride = gridDim.x * blockDim.x;
    for (int e = i; e < E; e += stride) atomicAdd(&cnt[dst[e]], 1);
}

__global__ void blocksum_kernel(const int* __restrict__ cnt, int* __restrict__ bsum) {
    __shared__ int s[256];
    int t = threadIdx.x;
    s[t] = cnt[blockIdx.x * 256 + t];
    __syncthreads();
    for (int off = 128; off > 0; off >>= 1) {
        if (t < off) s[t] += s[t + off];
        __syncthreads();
    }
    if (t == 0) bsum[blockIdx.x] = s[0];
}

__global__ void scansmall_kernel(int* __restrict__ bsum, int nb) {
    __shared__ int s[256];
    int t = threadIdx.x;
    int v = (t < nb) ? bsum[t] : 0;
    s[t] = v;
    __syncthreads();
    for (int off = 1; off < 256; off <<= 1) {
        int x = (t >= off) ? s[t - off] : 0;
        __syncthreads();
        s[t] += x;
        __syncthreads();
    }
    if (t < nb) bsum[t] = s[t] - v;   // exclusive
}

__global__ void scanfinal_kernel(const int* __restrict__ cnt, const int* __restrict__ bsum,
                                 int* __restrict__ offs, int* __restrict__ cur, int N) {
    __shared__ int s[256];
    int t = threadIdx.x;
    int i = blockIdx.x * 256 + t;
    int v = cnt[i];
    s[t] = v;
    __syncthreads();
    for (int off = 1; off < 256; off <<= 1) {
        int x = (t >= off) ? s[t - off] : 0;
        __syncthreads();
        s[t] += x;
        __syncthreads();
    }
    int incl = s[t];
    int base = bsum[blockIdx.x];
    int o = base + incl - v;
    offs[i] = o;
    cur[i] = o;
    if (i == N - 1) offs[N] = base + incl;
}

__global__ void fill_kernel(const int* __restrict__ src, const int* __restrict__ dst,
                            int* __restrict__ cur, int* __restrict__ col, int E) {
    int i = blockIdx.x * blockDim.x + threadIdx.x;
    int stride = gridDim.x * blockDim.x;
    for (int e = i; e < E; e += stride) {
        int d = dst[e];
        int p = atomicAdd(&cur[d], 1);
        col[p] = src[e];
    }
}

// ---- fused SAGE layer: gather-mean (bf16 in) + GEMV (f32) + relu (bf16 out)
// one wave handles NPW consecutive nodes; lane = feature/output index.
// Weights streamed per 4-k chunk (low VGPR), amortized over NPW nodes.
__global__ __launch_bounds__(256) void fused_layer2(
        const unsigned short* __restrict__ h, unsigned short* __restrict__ out,
        const int* __restrict__ offs, const int* __restrict__ col,
        const float* __restrict__ Wl, const float* __restrict__ Wr,
        const float* __restrict__ b, int N) {
    int lane = threadIdx.x & 63;
    int wid  = (blockIdx.x * blockDim.x + threadIdx.x) >> 6;
    int nw   = (gridDim.x * blockDim.x) >> 6;
    const float* wlp = Wl + lane * D;
    const float* wrp = Wr + lane * D;
    float bv = b[lane];

    for (int g0 = wid * NPW; g0 < N; g0 += nw * NPW) {
        float av[NPW], hv[NPW];
#pragma unroll
        for (int u = 0; u < NPW; ++u) {
            int beg = offs[g0 + u], end = offs[g0 + u + 1];
            float s0 = 0.f, s1 = 0.f;
            int e = beg;
            for (; e + 4 <= end; e += 4) {
                int c0 = col[e], c1 = col[e+1], c2 = col[e+2], c3 = col[e+3];
                float v0 = bf2f(h[(size_t)c0 * D + lane]);
                float v1 = bf2f(h[(size_t)c1 * D + lane]);
                float v2 = bf2f(h[(size_t)c2 * D + lane]);
                float v3 = bf2f(h[(size_t)c3 * D + lane]);
                s0 += v0 + v2;
                s1 += v1 + v3;
            }
            for (; e < end; ++e) s0 += bf2f(h[(size_t)col[e] * D + lane]);
            int deg = end - beg;
            av[u] = (deg > 0) ? (s0 + s1) / (float)deg : 0.f;
            hv[u] = bf2f(h[(size_t)(g0 + u) * D + lane]);
        }

        float o[NPW];
#pragma unroll
        for (int u = 0; u < NPW; ++u) o[u] = bv;
#pragma unroll 1
        for (int k4 = 0; k4 < D / 4; ++k4) {
            float4 wl4 = *(const float4*)(wlp + k4 * 4);
            float4 wr4 = *(const float4*)(wrp + k4 * 4);
            int kb = k4 * 4;
            float wls[4] = {wl4.x, wl4.y, wl4.z, wl4.w};
            float wrs[4] = {wr4.x, wr4.y, wr4.z, wr4.w};
#pragma unroll
            for (int t = 0; t < 4; ++t) {
#pragma unroll
                for (int u = 0; u < NPW; ++u) {
                    o[u] = fmaf(bcastf(av[u], kb + t), wls[t], o[u]);
                    o[u] = fmaf(bcastf(hv[u], kb + t), wrs[t], o[u]);
                }
            }
        }
#pragma unroll
        for (int u = 0; u < NPW; ++u)
            out[(size_t)(g0 + u) * D + lane] = f2bf(fmaxf(o[u], 0.f));
    }
}

// ---- final layer via linearity: project h3 to 4 scalars per node -----------
// z4[i] = { h3[i]·Wlo[0], h3[i]·Wlo[1], h3[i]·Wro[0], h3[i]·Wro[1] }
__global__ __launch_bounds__(256) void project_kernel(
        const unsigned short* __restrict__ h, const float* __restrict__ Wlo,
        const float* __restrict__ Wro, float4* __restrict__ z4, int N) {
    int lane = threadIdx.x & 63;
    int wid  = (blockIdx.x * blockDim.x + threadIdx.x) >> 6;
    int nw   = (gridDim.x * blockDim.x) >> 6;
    float wl0 = Wlo[lane], wl1 = Wlo[D + lane];
    float wr0 = Wro[lane], wr1 = Wro[D + lane];
    for (int i = wid; i < N; i += nw) {
        float hv = bf2f(h[(size_t)i * D + lane]);
        float a0 = hv * wl0, a1 = hv * wl1, a2 = hv * wr0, a3 = hv * wr1;
#pragma unroll
        for (int off = 32; off > 0; off >>= 1) {
            a0 += __shfl_xor(a0, off, 64);
            a1 += __shfl_xor(a1, off, 64);
            a2 += __shfl_xor(a2, off, 64);
            a3 += __shfl_xor(a3, off, 64);
        }
        if (lane == 0) z4[i] = make_float4(a0, a1, a2, a3);
    }
}

// gather z over edges (16B/edge, L2-resident), pool per graph via LDS
__global__ __launch_bounds__(256) void zpool_kernel(
        const float4* __restrict__ z4, const int* __restrict__ offs,
        const int* __restrict__ col, const int* __restrict__ batch,
        float* __restrict__ pool) {
    __shared__ float lp[NGRAPHS * 2];
    int t = threadIdx.x;
    lp[t] = 0.f;
    __syncthreads();
    int i0 = blockIdx.x * 256 + t;
    int stride = gridDim.x * 256;
    for (int i = i0; i < NNODES; i += stride) {
        int beg = offs[i], end = offs[i + 1];
        float s0 = 0.f, s1 = 0.f;
        for (int e = beg; e < end; ++e) {
            float4 z = z4[col[e]];
            s0 += z.x;
            s1 += z.y;
        }
        float inv = (end > beg) ? 1.f / (float)(end - beg) : 0.f;
        float4 zi = z4[i];
        int g = batch[i];
        atomicAdd(&lp[g * 2 + 0], s0 * inv + zi.z);
        atomicAdd(&lp[g * 2 + 1], s1 * inv + zi.w);
    }
    __syncthreads();
    float v = lp[t];
    if (v != 0.f) atomicAdd(&pool[t], v);
}

__global__ void out_kernel(const float* __restrict__ pool, const int* __restrict__ batch,
                           const float* __restrict__ bo, float* __restrict__ out) {
    int t = threadIdx.x;              // 256 = 128 graphs x 2 classes
    int g = t >> 1, j = t & 1;
    int start = lower_bound(batch, NNODES, g);
    int end   = lower_bound(batch, NNODES, g + 1);
    int c = end - start;
    out[t] = (c > 0) ? pool[t] / (float)c + bo[j] : 0.f;
}

// ---- launch ---------------------------------------------------------------

extern "C" void kernel_launch(void* const* d_in, const int* in_sizes, int n_in,
                              void* d_out, int out_size, void* d_ws, size_t ws_size,
                              hipStream_t stream) {
    const float* x    = (const float*)d_in[0];
    const int*   eidx = (const int*)d_in[1];
    const int*   batch= (const int*)d_in[2];
    const float* Wl   = (const float*)d_in[3];
    const float* Wr   = (const float*)d_in[4];
    const float* b    = (const float*)d_in[5];
    const float* Wlo  = (const float*)d_in[6];
    const float* Wro  = (const float*)d_in[7];
    const float* bo   = (const float*)d_in[8];

    int E = in_sizes[1] / 2;
    const int* src = eidx;
    const int* dst = eidx + E;

    char* ws = (char*)d_ws;
    size_t hb2 = (size_t)NNODES * D * 2;     // bf16 h buffer = 8,192,000 B
    unsigned short* xb   = (unsigned short*)ws;
    unsigned short* bufA = (unsigned short*)(ws + hb2);
    unsigned short* bufB = (unsigned short*)(ws + 2 * hb2);
    char* p = ws + 3 * hb2;
    int*    col  = (int*)p;    p += (size_t)E * 4;
    int*    offs = (int*)p;    p += ((size_t)(NNODES + 1) * 4 + 15) / 16 * 16;
    int*    cur  = (int*)p;    p += (size_t)NNODES * 4;
    int*    cnt  = (int*)p;    p += (size_t)NNODES * 4;
    int*    bsum = (int*)p;    p += 1024;
    float4* z4   = (float4*)p; p += (size_t)NNODES * 16;
    float*  pool = (float*)p;

    const int NB = NNODES / 256;     // 250

    hipMemsetAsync(cnt, 0, (size_t)NNODES * 4, stream);
    hipMemsetAsync(pool, 0, NGRAPHS * 2 * sizeof(float), stream);

    tobf_kernel<<<2048, 256, 0, stream>>>((const float4*)x, (ushort4*)xb, NNODES * D / 4);

    degree_kernel<<<1024, 256, 0, stream>>>(dst, E, cnt);
    blocksum_kernel<<<NB, 256, 0, stream>>>(cnt, bsum);
    scansmall_kernel<<<1, 256, 0, stream>>>(bsum, NB);
    scanfinal_kernel<<<NB, 256, 0, stream>>>(cnt, bsum, offs, cur, NNODES);
    fill_kernel<<<2048, 256, 0, stream>>>(src, dst, cur, col, E);

    const int LGRID = NNODES / NPW / 4;     // 2000 blocks -> one 8-node group per wave
    fused_layer2<<<LGRID, 256, 0, stream>>>(xb,   bufA, offs, col,
                                            Wl + 0 * D * D, Wr + 0 * D * D, b + 0 * D, NNODES);
    fused_layer2<<<LGRID, 256, 0, stream>>>(bufA, bufB, offs, col,
                                            Wl + 1 * D * D, Wr + 1 * D * D, b + 1 * D, NNODES);
    fused_layer2<<<LGRID, 256, 0, stream>>>(bufB, bufA, offs, col,
                                            Wl + 2 * D * D, Wr + 2 * D * D, b + 2 * D, NNODES);

    project_kernel<<<2048, 256, 0, stream>>>(bufA, Wlo, Wro, z4, NNODES);
    zpool_kernel<<<NB, 256, 0, stream>>>(z4, offs, col, batch, pool);
    out_kernel<<<1, 256, 0, stream>>>(pool, batch, bo, (float*)d_out);
}

// Round 4
// 334.996 us; speedup vs baseline: 4.0150x; 1.3748x over previous
//
#include <hip/hip_runtime.h>

#define NNODES 64000
#define NGRAPHS 128
#define D 64

typedef _Float16 half8 __attribute__((ext_vector_type(8)));
typedef float f32x4 __attribute__((ext_vector_type(4)));

__device__ __forceinline__ int lower_bound(const int* __restrict__ a, int n, int key) {
    int lo = 0, hi = n;
    while (lo < hi) {
        int mid = (lo + hi) >> 1;
        if (a[mid] < key) lo = mid + 1; else hi = mid;
    }
    return lo;
}

// ---- conversions -----------------------------------------------------------

__global__ void tohalf_kernel(const float4* __restrict__ x, half8* __restrict__ xh, int n8) {
    int i = blockIdx.x * blockDim.x + threadIdx.x;
    int st = gridDim.x * blockDim.x;
    for (; i < n8; i += st) {
        float4 a = x[2 * i], b = x[2 * i + 1];
        half8 o;
        o[0] = (_Float16)a.x; o[1] = (_Float16)a.y; o[2] = (_Float16)a.z; o[3] = (_Float16)a.w;
        o[4] = (_Float16)b.x; o[5] = (_Float16)b.y; o[6] = (_Float16)b.z; o[7] = (_Float16)b.w;
        xh[i] = o;
    }
}

// convert Wl (3*4096) and Wr (3*4096) to fp16
__global__ void wconv_kernel(const float* __restrict__ Wl, const float* __restrict__ Wr,
                             _Float16* __restrict__ Wlh, _Float16* __restrict__ Wrh) {
    int i = blockIdx.x * blockDim.x + threadIdx.x;   // 96 blocks * 256 = 24576
    if (i < 3 * D * D) {
        Wlh[i] = (_Float16)Wl[i];
        Wrh[i] = (_Float16)Wr[i];
    }
}

// ---- CSR build -------------------------------------------------------------

__global__ void degree_kernel(const int* __restrict__ dst, int E, int* __restrict__ cnt) {
    int i = blockIdx.x * blockDim.x + threadIdx.x;
    int stride = gridDim.x * blockDim.x;
    for (int e = i; e < E; e += stride) atomicAdd(&cnt[dst[e]], 1);
}

__global__ void blocksum_kernel(const int* __restrict__ cnt, int* __restrict__ bsum) {
    __shared__ int s[256];
    int t = threadIdx.x;
    s[t] = cnt[blockIdx.x * 256 + t];
    __syncthreads();
    for (int off = 128; off > 0; off >>= 1) {
        if (t < off) s[t] += s[t + off];
        __syncthreads();
    }
    if (t == 0) bsum[blockIdx.x] = s[0];
}

__global__ void scansmall_kernel(int* __restrict__ bsum, int nb) {
    __shared__ int s[256];
    int t = threadIdx.x;
    int v = (t < nb) ? bsum[t] : 0;
    s[t] = v;
    __syncthreads();
    for (int off = 1; off < 256; off <<= 1) {
        int x = (t >= off) ? s[t - off] : 0;
        __syncthreads();
        s[t] += x;
        __syncthreads();
    }
    if (t < nb) bsum[t] = s[t] - v;   // exclusive
}

__global__ void scanfinal_kernel(const int* __restrict__ cnt, const int* __restrict__ bsum,
                                 int* __restrict__ offs, int* __restrict__ cur, int N) {
    __shared__ int s[256];
    int t = threadIdx.x;
    int i = blockIdx.x * 256 + t;
    int v = cnt[i];
    s[t] = v;
    __syncthreads();
    for (int off = 1; off < 256; off <<= 1) {
        int x = (t >= off) ? s[t - off] : 0;
        __syncthreads();
        s[t] += x;
        __syncthreads();
    }
    int incl = s[t];
    int base = bsum[blockIdx.x];
    int o = base + incl - v;
    offs[i] = o;
    cur[i] = o;
    if (i == N - 1) offs[N] = base + incl;
}

__global__ void fill_kernel(const int* __restrict__ src, const int* __restrict__ dst,
                            int* __restrict__ cur, int* __restrict__ col, int E) {
    int i = blockIdx.x * blockDim.x + threadIdx.x;
    int stride = gridDim.x * blockDim.x;
    for (int e = i; e < E; e += stride) {
        int d = dst[e];
        int p = atomicAdd(&cur[d], 1);
        col[p] = src[e];
    }
}

// ---- neighbor mean: wave per node, 8 edges x 8 feature-chunks in parallel --
__global__ __launch_bounds__(256) void aggregate_kernel(
        const _Float16* __restrict__ h, _Float16* __restrict__ aggr,
        const int* __restrict__ offs, const int* __restrict__ col, int N) {
    int lane  = threadIdx.x & 63;
    int wid   = (blockIdx.x * blockDim.x + threadIdx.x) >> 6;
    int nw    = (gridDim.x * blockDim.x) >> 6;
    int eslot = lane >> 3;     // 0..7 edge slot
    int chunk = lane & 7;      // feature chunk (8 halfs)

    for (int i = wid; i < N; i += nw) {
        int beg = offs[i], end = offs[i + 1];
        float s[8] = {0.f, 0.f, 0.f, 0.f, 0.f, 0.f, 0.f, 0.f};
        for (int e0 = beg; e0 < end; e0 += 8) {
            int e = e0 + eslot;
            if (e < end) {
                int c = col[e];
                half8 v = *(const half8*)(h + (size_t)c * D + chunk * 8);
#pragma unroll
                for (int j = 0; j < 8; ++j) s[j] += (float)v[j];
            }
        }
#pragma unroll
        for (int off = 8; off <= 32; off <<= 1) {
#pragma unroll
            for (int j = 0; j < 8; ++j) s[j] += __shfl_xor(s[j], off, 64);
        }
        if (eslot == 0) {
            int deg = end - beg;
            float inv = deg > 0 ? 1.f / (float)deg : 0.f;
            half8 o;
#pragma unroll
            for (int j = 0; j < 8; ++j) o[j] = (_Float16)(s[j] * inv);
            *(half8*)(aggr + (size_t)i * D + chunk * 8) = o;
        }
    }
}

// ---- transform: out = relu([aggr|h] @ [Wl;Wr]^T + b), MFMA 16x16x32 f16 ----
// wave computes 16 rows x 64 cols; grid 1000 blocks x 4 waves = 64000 rows
__global__ __launch_bounds__(256) void transform_mfma(
        const _Float16* __restrict__ aggr, const _Float16* __restrict__ h,
        _Float16* __restrict__ out,
        const _Float16* __restrict__ Wlh, const _Float16* __restrict__ Wrh,
        const float* __restrict__ b) {
    int lane = threadIdx.x & 63;
    int w    = threadIdx.x >> 6;
    int row0 = (blockIdx.x * 4 + w) * 16;
    int r = lane & 15;        // A-row / B-col / C-col
    int g = lane >> 4;        // k-subgroup: holds k = g*8..g*8+7 within K=32

    half8 bf[4][4];
#pragma unroll
    for (int kt = 0; kt < 4; ++kt) {
        const _Float16* Wm = (kt < 2) ? Wlh : Wrh;
        int kk = (kt & 1) * 32 + g * 8;
#pragma unroll
        for (int nt = 0; nt < 4; ++nt)
            bf[kt][nt] = *(const half8*)(Wm + (size_t)(nt * 16 + r) * D + kk);
    }

    f32x4 acc[4];
#pragma unroll
    for (int nt = 0; nt < 4; ++nt) {
        float bv = b[nt * 16 + r];
        acc[nt] = (f32x4){bv, bv, bv, bv};
    }

#pragma unroll
    for (int kt = 0; kt < 4; ++kt) {
        const _Float16* src = (kt < 2) ? aggr : h;
        int kk = (kt & 1) * 32 + g * 8;
        half8 af = *(const half8*)(src + (size_t)(row0 + r) * D + kk);
#pragma unroll
        for (int nt = 0; nt < 4; ++nt)
            acc[nt] = __builtin_amdgcn_mfma_f32_16x16x32_f16(af, bf[kt][nt], acc[nt], 0, 0, 0);
    }

    // C/D: col = lane&15, row = (lane>>4)*4 + reg  [m89-verified]
#pragma unroll
    for (int nt = 0; nt < 4; ++nt) {
#pragma unroll
        for (int q = 0; q < 4; ++q) {
            int row = row0 + g * 4 + q;
            float v = fmaxf(acc[nt][q], 0.f);
            out[(size_t)row * D + nt * 16 + r] = (_Float16)v;
        }
    }
}

// ---- final layer via linearity: z12[i] = h3[i]@Wlo^T, z34[i] = h3[i]@Wro^T -
__global__ __launch_bounds__(256) void project_kernel(
        const _Float16* __restrict__ h, const float* __restrict__ Wlo,
        const float* __restrict__ Wro, float2* __restrict__ z12,
        float2* __restrict__ z34, int N) {
    int lane = threadIdx.x & 63;
    int wid  = (blockIdx.x * blockDim.x + threadIdx.x) >> 6;
    int nw   = (gridDim.x * blockDim.x) >> 6;
    float wl0 = Wlo[lane], wl1 = Wlo[D + lane];
    float wr0 = Wro[lane], wr1 = Wro[D + lane];
    for (int i = wid; i < N; i += nw) {
        float hv = (float)h[(size_t)i * D + lane];
        float a0 = hv * wl0, a1 = hv * wl1, a2 = hv * wr0, a3 = hv * wr1;
#pragma unroll
        for (int off = 1; off <= 32; off <<= 1) {
            a0 += __shfl_xor(a0, off, 64);
            a1 += __shfl_xor(a1, off, 64);
            a2 += __shfl_xor(a2, off, 64);
            a3 += __shfl_xor(a3, off, 64);
        }
        if (lane == 0) {
            z12[i] = make_float2(a0, a1);
            z34[i] = make_float2(a2, a3);
        }
    }
}

// wave per node: lane-per-edge gather of z12, shuffle reduce, LDS pool -------
__global__ __launch_bounds__(256) void zpool_kernel(
        const float2* __restrict__ z12, const float2* __restrict__ z34,
        const int* __restrict__ offs, const int* __restrict__ col,
        const int* __restrict__ batch, float* __restrict__ pool) {
    __shared__ float lp[NGRAPHS * 2];
    int t = threadIdx.x;
    lp[t] = 0.f;
    __syncthreads();
    int lane = t & 63;
    int wid  = (blockIdx.x * blockDim.x + t) >> 6;
    int nw   = (gridDim.x * blockDim.x) >> 6;
    for (int i = wid; i < NNODES; i += nw) {
        int beg = offs[i], end = offs[i + 1];
        float s0 = 0.f, s1 = 0.f;
        for (int e0 = beg; e0 < end; e0 += 64) {
            int e = e0 + lane;
            if (e < end) {
                float2 z = z12[col[e]];
                s0 += z.x; s1 += z.y;
            }
        }
#pragma unroll
        for (int off = 1; off <= 32; off <<= 1) {
            s0 += __shfl_xor(s0, off, 64);
            s1 += __shfl_xor(s1, off, 64);
        }
        if (lane == 0) {
            int deg = end - beg;
            float inv = deg > 0 ? 1.f / (float)deg : 0.f;
            float2 zi = z34[i];
            int gg = batch[i];
            atomicAdd(&lp[gg * 2 + 0], s0 * inv + zi.x);
            atomicAdd(&lp[gg * 2 + 1], s1 * inv + zi.y);
        }
    }
    __syncthreads();
    float v = lp[t];
    if (v != 0.f) atomicAdd(&pool[t], v);
}

__global__ void out_kernel(const float* __restrict__ pool, const int* __restrict__ batch,
                           const float* __restrict__ bo, float* __restrict__ out) {
    int t = threadIdx.x;              // 256 = 128 graphs x 2 classes
    int g = t >> 1, j = t & 1;
    int start = lower_bound(batch, NNODES, g);
    int end   = lower_bound(batch, NNODES, g + 1);
    int c = end - start;
    out[t] = (c > 0) ? pool[t] / (float)c + bo[j] : 0.f;
}

// ---- launch ---------------------------------------------------------------

extern "C" void kernel_launch(void* const* d_in, const int* in_sizes, int n_in,
                              void* d_out, int out_size, void* d_ws, size_t ws_size,
                              hipStream_t stream) {
    const float* x    = (const float*)d_in[0];
    const int*   eidx = (const int*)d_in[1];
    const int*   batch= (const int*)d_in[2];
    const float* Wl   = (const float*)d_in[3];
    const float* Wr   = (const float*)d_in[4];
    const float* b    = (const float*)d_in[5];
    const float* Wlo  = (const float*)d_in[6];
    const float* Wro  = (const float*)d_in[7];
    const float* bo   = (const float*)d_in[8];

    int E = in_sizes[1] / 2;
    const int* src = eidx;
    const int* dst = eidx + E;

    char* ws = (char*)d_ws;
    size_t hb = (size_t)NNODES * D * 2;       // fp16 h buffer = 8,192,000 B
    _Float16* xh   = (_Float16*)ws;
    _Float16* bufA = (_Float16*)(ws + hb);
    _Float16* bufB = (_Float16*)(ws + 2 * hb);
    char* p = ws + 3 * hb;
    _Float16* Wlh  = (_Float16*)p;  p += 3 * D * D * 2;
    _Float16* Wrh  = (_Float16*)p;  p += 3 * D * D * 2;
    int*    col  = (int*)p;     p += (size_t)E * 4;
    int*    offs = (int*)p;     p += ((size_t)(NNODES + 1) * 4 + 15) / 16 * 16;
    int*    cur  = (int*)p;     p += (size_t)NNODES * 4;
    int*    cnt  = (int*)p;     p += (size_t)NNODES * 4;
    int*    bsum = (int*)p;     p += 1024;
    float2* z12  = (float2*)p;  p += (size_t)NNODES * 8;
    float2* z34  = (float2*)p;  p += (size_t)NNODES * 8;
    float*  pool = (float*)p;

    const int NB = NNODES / 256;     // 250

    hipMemsetAsync(cnt, 0, (size_t)NNODES * 4, stream);
    hipMemsetAsync(pool, 0, NGRAPHS * 2 * sizeof(float), stream);

    tohalf_kernel<<<2000, 256, 0, stream>>>((const float4*)x, (half8*)xh, NNODES * D / 8);
    wconv_kernel<<<96, 256, 0, stream>>>(Wl, Wr, Wlh, Wrh);

    degree_kernel<<<1024, 256, 0, stream>>>(dst, E, cnt);
    blocksum_kernel<<<NB, 256, 0, stream>>>(cnt, bsum);
    scansmall_kernel<<<1, 256, 0, stream>>>(bsum, NB);
    scanfinal_kernel<<<NB, 256, 0, stream>>>(cnt, bsum, offs, cur, NNODES);
    fill_kernel<<<2048, 256, 0, stream>>>(src, dst, cur, col, E);

    // L1: aggr(xh)->bufA ; out = bufB
    aggregate_kernel<<<2000, 256, 0, stream>>>(xh, bufA, offs, col, NNODES);
    transform_mfma<<<1000, 256, 0, stream>>>(bufA, xh, bufB, Wlh, Wrh, b);
    // L2: aggr(bufB)->bufA ; out = xh (x no longer needed)
    aggregate_kernel<<<2000, 256, 0, stream>>>(bufB, bufA, offs, col, NNODES);
    transform_mfma<<<1000, 256, 0, stream>>>(bufA, bufB, xh, Wlh + D * D, Wrh + D * D, b + D);
    // L3: aggr(xh)->bufA ; out = bufB
    aggregate_kernel<<<2000, 256, 0, stream>>>(xh, bufA, offs, col, NNODES);
    transform_mfma<<<1000, 256, 0, stream>>>(bufA, xh, bufB, Wlh + 2 * D * D, Wrh + 2 * D * D, b + 2 * D);

    project_kernel<<<2048, 256, 0, stream>>>(bufB, Wlo, Wro, z12, z34, NNODES);
    zpool_kernel<<<500, 256, 0, stream>>>(z12, z34, offs, col, batch, pool);
    out_kernel<<<1, 256, 0, stream>>>(pool, batch, bo, (float*)d_out);
}

// Round 5
// 264.541 us; speedup vs baseline: 5.0843x; 1.2663x over previous
//
#include <hip/hip_runtime.h>

#define NNODES 64000
#define NGRAPHS 128
#define D 64
#define NXCD 8

typedef _Float16 half8 __attribute__((ext_vector_type(8)));
typedef float f32x4 __attribute__((ext_vector_type(4)));

__device__ __forceinline__ int lower_bound(const int* __restrict__ a, int n, int key) {
    int lo = 0, hi = n;
    while (lo < hi) {
        int mid = (lo + hi) >> 1;
        if (a[mid] < key) lo = mid + 1; else hi = mid;
    }
    return lo;
}

// ---- conversions -----------------------------------------------------------

__global__ void tohalf_kernel(const float4* __restrict__ x, half8* __restrict__ xh, int n8) {
    int i = blockIdx.x * blockDim.x + threadIdx.x;
    int st = gridDim.x * blockDim.x;
    for (; i < n8; i += st) {
        float4 a = x[2 * i], b = x[2 * i + 1];
        half8 o;
        o[0] = (_Float16)a.x; o[1] = (_Float16)a.y; o[2] = (_Float16)a.z; o[3] = (_Float16)a.w;
        o[4] = (_Float16)b.x; o[5] = (_Float16)b.y; o[6] = (_Float16)b.z; o[7] = (_Float16)b.w;
        xh[i] = o;
    }
}

__global__ void wconv_kernel(const float* __restrict__ Wl, const float* __restrict__ Wr,
                             _Float16* __restrict__ Wlh, _Float16* __restrict__ Wrh) {
    int i = blockIdx.x * blockDim.x + threadIdx.x;   // 96*256 = 24576 >= 3*64*64
    if (i < 3 * D * D) {
        Wlh[i] = (_Float16)Wl[i];
        Wrh[i] = (_Float16)Wr[i];
    }
}

// ---- CSR build -------------------------------------------------------------

__global__ void degree_kernel(const int* __restrict__ dst, int E, int* __restrict__ cnt) {
    int i = blockIdx.x * blockDim.x + threadIdx.x;
    int stride = gridDim.x * blockDim.x;
    for (int e = i; e < E; e += stride) atomicAdd(&cnt[dst[e]], 1);
}

__global__ void blocksum_kernel(const int* __restrict__ cnt, int* __restrict__ bsum) {
    __shared__ int s[256];
    int t = threadIdx.x;
    s[t] = cnt[blockIdx.x * 256 + t];
    __syncthreads();
    for (int off = 128; off > 0; off >>= 1) {
        if (t < off) s[t] += s[t + off];
        __syncthreads();
    }
    if (t == 0) bsum[blockIdx.x] = s[0];
}

__global__ void scansmall_kernel(int* __restrict__ bsum, int nb) {
    __shared__ int s[256];
    int t = threadIdx.x;
    int v = (t < nb) ? bsum[t] : 0;
    s[t] = v;
    __syncthreads();
    for (int off = 1; off < 256; off <<= 1) {
        int x = (t >= off) ? s[t - off] : 0;
        __syncthreads();
        s[t] += x;
        __syncthreads();
    }
    if (t < nb) bsum[t] = s[t] - v;   // exclusive
}

__global__ void scanfinal_kernel(const int* __restrict__ cnt, const int* __restrict__ bsum,
                                 int* __restrict__ offs, int* __restrict__ cur, int N) {
    __shared__ int s[256];
    int t = threadIdx.x;
    int i = blockIdx.x * 256 + t;
    int v = cnt[i];
    s[t] = v;
    __syncthreads();
    for (int off = 1; off < 256; off <<= 1) {
        int x = (t >= off) ? s[t - off] : 0;
        __syncthreads();
        s[t] += x;
        __syncthreads();
    }
    int incl = s[t];
    int base = bsum[blockIdx.x];
    int o = base + incl - v;
    offs[i] = o;
    cur[i] = o;
    if (i == N - 1) offs[N] = base + incl;
}

// XCD-local fill: team (blockIdx%8) claims only dst in its 8000-node range, so
// each col/cur cache line is dirtied by a single XCD (kills ~17x write amp).
__global__ void fill_xcd(const int* __restrict__ src, const int* __restrict__ dst,
                         int* __restrict__ cur, int* __restrict__ col, int E) {
    int team = blockIdx.x & (NXCD - 1);
    int sub  = blockIdx.x >> 3;
    int nsub = gridDim.x >> 3;
    int lo = team * (NNODES / NXCD), hi = lo + NNODES / NXCD;
    for (int e = sub * 256 + threadIdx.x; e < E; e += nsub * 256) {
        int d = dst[e];
        if (d >= lo && d < hi) {
            int p = atomicAdd(&cur[d], 1);
            col[p] = src[e];
        }
    }
}

// ---- fused layer: gather-mean -> LDS tile -> MFMA transform (+optional proj)
// block = 4 waves; wave owns 16 consecutive nodes (one MFMA row-tile).
// PRJ: layer-3 variant — skip out write, emit z12/z34 = h3 @ Wlo^T / Wro^T.
template <int PRJ>
__global__ __launch_bounds__(256) void layer_fused(
        const _Float16* __restrict__ h, _Float16* __restrict__ out,
        const int* __restrict__ offs, const int* __restrict__ col,
        const _Float16* __restrict__ Wlh, const _Float16* __restrict__ Wrh,
        const float* __restrict__ b,
        const float* __restrict__ Wlo, const float* __restrict__ Wro,
        float* __restrict__ z12, float* __restrict__ z34) {
    __shared__ _Float16 tile[4][16][D];          // 8 KB: per-wave 16x64 staging
    int lane = threadIdx.x & 63;
    int w    = threadIdx.x >> 6;
    int row0 = (blockIdx.x * 4 + w) * 16;

    // phase A: aggregate 16 nodes (8 per pass); lane = (node-slot, 8-feat chunk)
    int ns = lane >> 3;
    int ch = lane & 7;
#pragma unroll
    for (int pass = 0; pass < 2; ++pass) {
        int i = row0 + pass * 8 + ns;
        int beg = offs[i], end = offs[i + 1];
        float s[8] = {0.f, 0.f, 0.f, 0.f, 0.f, 0.f, 0.f, 0.f};
        int e = beg;
        for (; e + 2 <= end; e += 2) {
            int c0 = col[e], c1 = col[e + 1];
            half8 v0 = *(const half8*)(h + (size_t)c0 * D + ch * 8);
            half8 v1 = *(const half8*)(h + (size_t)c1 * D + ch * 8);
#pragma unroll
            for (int j = 0; j < 8; ++j) s[j] += (float)v0[j] + (float)v1[j];
        }
        if (e < end) {
            half8 v = *(const half8*)(h + (size_t)col[e] * D + ch * 8);
#pragma unroll
            for (int j = 0; j < 8; ++j) s[j] += (float)v[j];
        }
        float inv = (end > beg) ? 1.f / (float)(end - beg) : 0.f;
        half8 o;
#pragma unroll
        for (int j = 0; j < 8; ++j) o[j] = (_Float16)(s[j] * inv);
        *(half8*)(&tile[w][pass * 8 + ns][ch * 8]) = o;
    }
    // wave-private tile; DS ops complete in issue order per wave -> no barrier.

    int r = lane & 15;        // A-row / B-col / C-col
    int g = lane >> 4;        // k-subgroup

    // B fragments: [Wl;Wr] rows, K=128 split in 4 chunks of 32
    half8 bf[4][4];
#pragma unroll
    for (int kt = 0; kt < 4; ++kt) {
        const _Float16* Wm = (kt < 2) ? Wlh : Wrh;
        int kk = (kt & 1) * 32 + g * 8;
#pragma unroll
        for (int nt = 0; nt < 4; ++nt)
            bf[kt][nt] = *(const half8*)(Wm + (size_t)(nt * 16 + r) * D + kk);
    }

    f32x4 acc[4];
#pragma unroll
    for (int nt = 0; nt < 4; ++nt) {
        float bv = b[nt * 16 + r];
        acc[nt] = (f32x4){bv, bv, bv, bv};
    }

#pragma unroll
    for (int kt = 0; kt < 4; ++kt) {
        int kk = (kt & 1) * 32 + g * 8;
        half8 af;
        if (kt < 2) af = *(const half8*)(&tile[w][r][kk]);                 // aggr
        else        af = *(const half8*)(h + (size_t)(row0 + r) * D + kk); // self
#pragma unroll
        for (int nt = 0; nt < 4; ++nt)
            acc[nt] = __builtin_amdgcn_mfma_f32_16x16x32_f16(af, bf[kt][nt], acc[nt], 0, 0, 0);
    }

    // epilogue. C/D: col = lane&15, row = (lane>>4)*4 + q  [m89-verified]
    if (!PRJ) {
#pragma unroll
        for (int nt = 0; nt < 4; ++nt)
#pragma unroll
            for (int q = 0; q < 4; ++q) {
                int row = row0 + g * 4 + q;
                out[(size_t)row * D + nt * 16 + r] = (_Float16)fmaxf(acc[nt][q], 0.f);
            }
    } else {
        // stage relu(out) tile back to LDS (wave-private, in-order DS)
#pragma unroll
        for (int nt = 0; nt < 4; ++nt)
#pragma unroll
            for (int q = 0; q < 4; ++q)
                tile[w][g * 4 + q][nt * 16 + r] = (_Float16)fmaxf(acc[nt][q], 0.f);

        // B-frag of P rows {Wlo0,Wlo1,Wro0,Wro1} in cols 0..3
        half8 pf[2];
#pragma unroll
        for (int kt = 0; kt < 2; ++kt) {
            half8 t = {0, 0, 0, 0, 0, 0, 0, 0};
            if (r < 4) {
                const float* Pr = (r < 2) ? (Wlo + r * D) : (Wro + (r - 2) * D);
                int kk = kt * 32 + g * 8;
#pragma unroll
                for (int j = 0; j < 8; ++j) t[j] = (_Float16)Pr[kk + j];
            }
            pf[kt] = t;
        }
        f32x4 az = (f32x4){0.f, 0.f, 0.f, 0.f};
#pragma unroll
        for (int kt = 0; kt < 2; ++kt) {
            half8 af = *(const half8*)(&tile[w][r][kt * 32 + g * 8]);
            az = __builtin_amdgcn_mfma_f32_16x16x32_f16(af, pf[kt], az, 0, 0, 0);
        }
#pragma unroll
        for (int q = 0; q < 4; ++q) {
            int row = row0 + g * 4 + q;
            if (r < 2)      z12[row * 2 + r]       = az[q];
            else if (r < 4) z34[row * 2 + (r - 2)] = az[q];
        }
    }
}

// wave per node: lane-per-edge gather of z12, shuffle reduce, LDS pool -------
__global__ __launch_bounds__(256) void zpool_kernel(
        const float2* __restrict__ z12, const float2* __restrict__ z34,
        const int* __restrict__ offs, const int* __restrict__ col,
        const int* __restrict__ batch, float* __restrict__ pool) {
    __shared__ float lp[NGRAPHS * 2];
    int t = threadIdx.x;
    lp[t] = 0.f;
    __syncthreads();
    int lane = t & 63;
    int wid  = (blockIdx.x * blockDim.x + t) >> 6;
    int nw   = (gridDim.x * blockDim.x) >> 6;
    for (int i = wid; i < NNODES; i += nw) {
        int beg = offs[i], end = offs[i + 1];
        float s0 = 0.f, s1 = 0.f;
        for (int e0 = beg; e0 < end; e0 += 64) {
            int e = e0 + lane;
            if (e < end) {
                float2 z = z12[col[e]];
                s0 += z.x; s1 += z.y;
            }
        }
#pragma unroll
        for (int off = 1; off <= 32; off <<= 1) {
            s0 += __shfl_xor(s0, off, 64);
            s1 += __shfl_xor(s1, off, 64);
        }
        if (lane == 0) {
            int deg = end - beg;
            float inv = deg > 0 ? 1.f / (float)deg : 0.f;
            float2 zi = z34[i];
            int gg = batch[i];
            atomicAdd(&lp[gg * 2 + 0], s0 * inv + zi.x);
            atomicAdd(&lp[gg * 2 + 1], s1 * inv + zi.y);
        }
    }
    __syncthreads();
    float v = lp[t];
    if (v != 0.f) atomicAdd(&pool[t], v);
}

__global__ void out_kernel(const float* __restrict__ pool, const int* __restrict__ batch,
                           const float* __restrict__ bo, float* __restrict__ out) {
    int t = threadIdx.x;              // 256 = 128 graphs x 2 classes
    int g = t >> 1, j = t & 1;
    int start = lower_bound(batch, NNODES, g);
    int end   = lower_bound(batch, NNODES, g + 1);
    int c = end - start;
    out[t] = (c > 0) ? pool[t] / (float)c + bo[j] : 0.f;
}

// ---- launch ---------------------------------------------------------------

extern "C" void kernel_launch(void* const* d_in, const int* in_sizes, int n_in,
                              void* d_out, int out_size, void* d_ws, size_t ws_size,
                              hipStream_t stream) {
    const float* x    = (const float*)d_in[0];
    const int*   eidx = (const int*)d_in[1];
    const int*   batch= (const int*)d_in[2];
    const float* Wl   = (const float*)d_in[3];
    const float* Wr   = (const float*)d_in[4];
    const float* b    = (const float*)d_in[5];
    const float* Wlo  = (const float*)d_in[6];
    const float* Wro  = (const float*)d_in[7];
    const float* bo   = (const float*)d_in[8];

    int E = in_sizes[1] / 2;
    const int* src = eidx;
    const int* dst = eidx + E;

    char* ws = (char*)d_ws;
    size_t hb = (size_t)NNODES * D * 2;       // fp16 h buffer = 8,192,000 B
    _Float16* xh   = (_Float16*)ws;
    _Float16* bufA = (_Float16*)(ws + hb);
    char* p = ws + 2 * hb;
    _Float16* Wlh  = (_Float16*)p;  p += 3 * D * D * 2;
    _Float16* Wrh  = (_Float16*)p;  p += 3 * D * D * 2;
    int*    col  = (int*)p;     p += (size_t)E * 4;
    int*    offs = (int*)p;     p += ((size_t)(NNODES + 1) * 4 + 15) / 16 * 16;
    int*    cur  = (int*)p;     p += (size_t)NNODES * 4;
    int*    cnt  = (int*)p;     p += (size_t)NNODES * 4;
    int*    bsum = (int*)p;     p += 1024;
    float*  z12  = (float*)p;   p += (size_t)NNODES * 8;
    float*  z34  = (float*)p;   p += (size_t)NNODES * 8;
    float*  pool = (float*)p;

    const int NB = NNODES / 256;     // 250

    hipMemsetAsync(cnt, 0, (size_t)NNODES * 4, stream);
    hipMemsetAsync(pool, 0, NGRAPHS * 2 * sizeof(float), stream);

    tohalf_kernel<<<2000, 256, 0, stream>>>((const float4*)x, (half8*)xh, NNODES * D / 8);
    wconv_kernel<<<96, 256, 0, stream>>>(Wl, Wr, Wlh, Wrh);

    degree_kernel<<<1024, 256, 0, stream>>>(dst, E, cnt);
    blocksum_kernel<<<NB, 256, 0, stream>>>(cnt, bsum);
    scansmall_kernel<<<1, 256, 0, stream>>>(bsum, NB);
    scanfinal_kernel<<<NB, 256, 0, stream>>>(cnt, bsum, offs, cur, NNODES);
    fill_xcd<<<1024, 256, 0, stream>>>(src, dst, cur, col, E);

    // L1: xh -> bufA ; L2: bufA -> xh ; L3: xh -> z12/z34 (no h3 materialized)
    layer_fused<0><<<1000, 256, 0, stream>>>(xh,   bufA, offs, col,
                                             Wlh,             Wrh,             b,
                                             nullptr, nullptr, nullptr, nullptr);
    layer_fused<0><<<1000, 256, 0, stream>>>(bufA, xh,   offs, col,
                                             Wlh + D * D,     Wrh + D * D,     b + D,
                                             nullptr, nullptr, nullptr, nullptr);
    layer_fused<1><<<1000, 256, 0, stream>>>(xh,   bufA, offs, col,
                                             Wlh + 2 * D * D, Wrh + 2 * D * D, b + 2 * D,
                                             Wlo, Wro, z12, z34);

    zpool_kernel<<<500, 256, 0, stream>>>((const float2*)z12, (const float2*)z34,
                                          offs, col, batch, pool);
    out_kernel<<<1, 256, 0, stream>>>(pool, batch, bo, (float*)d_out);
}

// Round 6
// 247.079 us; speedup vs baseline: 5.4437x; 1.0707x over previous
//
#include <hip/hip_runtime.h>

#define NNODES 64000
#define NGRAPHS 128
#define D 64
#define NXCD 8

typedef _Float16 half8 __attribute__((ext_vector_type(8)));
typedef float f32x4 __attribute__((ext_vector_type(4)));

__device__ __forceinline__ int lower_bound(const int* __restrict__ a, int n, int key) {
    int lo = 0, hi = n;
    while (lo < hi) {
        int mid = (lo + hi) >> 1;
        if (a[mid] < key) lo = mid + 1; else hi = mid;
    }
    return lo;
}

// ---- conversions -----------------------------------------------------------

__global__ void tohalf_kernel(const float4* __restrict__ x, half8* __restrict__ xh, int n8,
                              const float* __restrict__ Wl, const float* __restrict__ Wr,
                              _Float16* __restrict__ Wlh, _Float16* __restrict__ Wrh) {
    int i = blockIdx.x * blockDim.x + threadIdx.x;
    int st = gridDim.x * blockDim.x;
    for (; i < n8; i += st) {
        float4 a = x[2 * i], b = x[2 * i + 1];
        half8 o;
        o[0] = (_Float16)a.x; o[1] = (_Float16)a.y; o[2] = (_Float16)a.z; o[3] = (_Float16)a.w;
        o[4] = (_Float16)b.x; o[5] = (_Float16)b.y; o[6] = (_Float16)b.z; o[7] = (_Float16)b.w;
        xh[i] = o;
    }
    int j = blockIdx.x * blockDim.x + threadIdx.x;
    if (j < 3 * D * D) {
        Wlh[j] = (_Float16)Wl[j];
        Wrh[j] = (_Float16)Wr[j];
    }
}

// ---- CSR build -------------------------------------------------------------

__global__ void degree_kernel(const int* __restrict__ dst, int E, int* __restrict__ cnt) {
    int i = blockIdx.x * blockDim.x + threadIdx.x;
    int stride = gridDim.x * blockDim.x;
    for (int e = i; e < E; e += stride) atomicAdd(&cnt[dst[e]], 1);
}

__global__ void blocksum_kernel(const int* __restrict__ cnt, int* __restrict__ bsum) {
    __shared__ int s[256];
    int t = threadIdx.x;
    s[t] = cnt[blockIdx.x * 256 + t];
    __syncthreads();
    for (int off = 128; off > 0; off >>= 1) {
        if (t < off) s[t] += s[t + off];
        __syncthreads();
    }
    if (t == 0) bsum[blockIdx.x] = s[0];
}

__global__ void scansmall_kernel(int* __restrict__ bsum, int nb) {
    __shared__ int s[256];
    int t = threadIdx.x;
    int v = (t < nb) ? bsum[t] : 0;
    s[t] = v;
    __syncthreads();
    for (int off = 1; off < 256; off <<= 1) {
        int x = (t >= off) ? s[t - off] : 0;
        __syncthreads();
        s[t] += x;
        __syncthreads();
    }
    if (t < nb) bsum[t] = s[t] - v;   // exclusive
}

// per-block scan + base -> offs/cur; also packs info[i] = {batch[i], invdeg}
__global__ void scanfinal_kernel(const int* __restrict__ cnt, const int* __restrict__ bsum,
                                 const int* __restrict__ batch,
                                 int* __restrict__ offs, int* __restrict__ cur,
                                 int2* __restrict__ info, int N) {
    __shared__ int s[256];
    int t = threadIdx.x;
    int i = blockIdx.x * 256 + t;
    int v = cnt[i];
    s[t] = v;
    __syncthreads();
    for (int off = 1; off < 256; off <<= 1) {
        int x = (t >= off) ? s[t - off] : 0;
        __syncthreads();
        s[t] += x;
        __syncthreads();
    }
    int incl = s[t];
    int base = bsum[blockIdx.x];
    int o = base + incl - v;
    offs[i] = o;
    cur[i] = o;
    float inv = (v > 0) ? 1.f / (float)v : 0.f;
    info[i] = make_int2(batch[i], __float_as_int(inv));
    if (i == N - 1) offs[N] = base + incl;
}

// XCD-local fill: team (blockIdx%8) claims only dst in its 8000-node range, so
// each col/cur cache line is dirtied by a single XCD (kills ~17x write amp).
__global__ void fill_xcd(const int* __restrict__ src, const int* __restrict__ dst,
                         int* __restrict__ cur, int* __restrict__ col, int E) {
    int team = blockIdx.x & (NXCD - 1);
    int sub  = blockIdx.x >> 3;
    int nsub = gridDim.x >> 3;
    int lo = team * (NNODES / NXCD), hi = lo + NNODES / NXCD;
    for (int e = sub * 256 + threadIdx.x; e < E; e += nsub * 256) {
        int d = dst[e];
        if (d >= lo && d < hi) {
            int p = atomicAdd(&cur[d], 1);
            col[p] = src[e];
        }
    }
}

// ---- fused layer: gather-mean -> LDS tile -> MFMA transform (+optional proj)
// block = 4 waves; wave owns 16 consecutive nodes (one MFMA row-tile).
// PRJ: layer-3 variant — skip out write, emit z12/z34 = h3 @ Wlo^T / Wro^T.
template <int PRJ>
__global__ __launch_bounds__(256) void layer_fused(
        const _Float16* __restrict__ h, _Float16* __restrict__ out,
        const int* __restrict__ offs, const int* __restrict__ col,
        const _Float16* __restrict__ Wlh, const _Float16* __restrict__ Wrh,
        const float* __restrict__ b,
        const float* __restrict__ Wlo, const float* __restrict__ Wro,
        float* __restrict__ z12, float* __restrict__ z34) {
    __shared__ _Float16 tile[4][16][D];          // 8 KB: per-wave 16x64 staging
    int lane = threadIdx.x & 63;
    int w    = threadIdx.x >> 6;
    int row0 = (blockIdx.x * 4 + w) * 16;

    // phase A: aggregate 16 nodes (8 per pass); lane = (node-slot, 8-feat chunk)
    int ns = lane >> 3;
    int ch = lane & 7;
#pragma unroll
    for (int pass = 0; pass < 2; ++pass) {
        int i = row0 + pass * 8 + ns;
        int beg = offs[i], end = offs[i + 1];
        float s[8] = {0.f, 0.f, 0.f, 0.f, 0.f, 0.f, 0.f, 0.f};
        int e = beg;
        for (; e + 4 <= end; e += 4) {     // 4 independent row loads in flight
            int c0 = col[e], c1 = col[e + 1], c2 = col[e + 2], c3 = col[e + 3];
            half8 v0 = *(const half8*)(h + (size_t)c0 * D + ch * 8);
            half8 v1 = *(const half8*)(h + (size_t)c1 * D + ch * 8);
            half8 v2 = *(const half8*)(h + (size_t)c2 * D + ch * 8);
            half8 v3 = *(const half8*)(h + (size_t)c3 * D + ch * 8);
#pragma unroll
            for (int j = 0; j < 8; ++j)
                s[j] += ((float)v0[j] + (float)v1[j]) + ((float)v2[j] + (float)v3[j]);
        }
        for (; e < end; ++e) {
            half8 v = *(const half8*)(h + (size_t)col[e] * D + ch * 8);
#pragma unroll
            for (int j = 0; j < 8; ++j) s[j] += (float)v[j];
        }
        float inv = (end > beg) ? 1.f / (float)(end - beg) : 0.f;
        half8 o;
#pragma unroll
        for (int j = 0; j < 8; ++j) o[j] = (_Float16)(s[j] * inv);
        *(half8*)(&tile[w][pass * 8 + ns][ch * 8]) = o;
    }
    // wave-private tile; DS ops complete in issue order per wave -> no barrier.

    int r = lane & 15;        // A-row / B-col / C-col
    int g = lane >> 4;        // k-subgroup

    // B fragments: [Wl;Wr] rows, K=128 split in 4 chunks of 32
    half8 bf[4][4];
#pragma unroll
    for (int kt = 0; kt < 4; ++kt) {
        const _Float16* Wm = (kt < 2) ? Wlh : Wrh;
        int kk = (kt & 1) * 32 + g * 8;
#pragma unroll
        for (int nt = 0; nt < 4; ++nt)
            bf[kt][nt] = *(const half8*)(Wm + (size_t)(nt * 16 + r) * D + kk);
    }

    f32x4 acc[4];
#pragma unroll
    for (int nt = 0; nt < 4; ++nt) {
        float bv = b[nt * 16 + r];
        acc[nt] = (f32x4){bv, bv, bv, bv};
    }

#pragma unroll
    for (int kt = 0; kt < 4; ++kt) {
        int kk = (kt & 1) * 32 + g * 8;
        half8 af;
        if (kt < 2) af = *(const half8*)(&tile[w][r][kk]);                 // aggr
        else        af = *(const half8*)(h + (size_t)(row0 + r) * D + kk); // self
#pragma unroll
        for (int nt = 0; nt < 4; ++nt)
            acc[nt] = __builtin_amdgcn_mfma_f32_16x16x32_f16(af, bf[kt][nt], acc[nt], 0, 0, 0);
    }

    // epilogue. C/D: col = lane&15, row = (lane>>4)*4 + q  [m89-verified]
    if (!PRJ) {
#pragma unroll
        for (int nt = 0; nt < 4; ++nt)
#pragma unroll
            for (int q = 0; q < 4; ++q) {
                int row = row0 + g * 4 + q;
                out[(size_t)row * D + nt * 16 + r] = (_Float16)fmaxf(acc[nt][q], 0.f);
            }
    } else {
        // stage relu(out) tile back to LDS (wave-private, in-order DS)
#pragma unroll
        for (int nt = 0; nt < 4; ++nt)
#pragma unroll
            for (int q = 0; q < 4; ++q)
                tile[w][g * 4 + q][nt * 16 + r] = (_Float16)fmaxf(acc[nt][q], 0.f);

        // B-frag of P rows {Wlo0,Wlo1,Wro0,Wro1} in cols 0..3
        half8 pf[2];
#pragma unroll
        for (int kt = 0; kt < 2; ++kt) {
            half8 t = {0, 0, 0, 0, 0, 0, 0, 0};
            if (r < 4) {
                const float* Pr = (r < 2) ? (Wlo + r * D) : (Wro + (r - 2) * D);
                int kk = kt * 32 + g * 8;
#pragma unroll
                for (int j = 0; j < 8; ++j) t[j] = (_Float16)Pr[kk + j];
            }
            pf[kt] = t;
        }
        f32x4 az = (f32x4){0.f, 0.f, 0.f, 0.f};
#pragma unroll
        for (int kt = 0; kt < 2; ++kt) {
            half8 af = *(const half8*)(&tile[w][r][kt * 32 + g * 8]);
            az = __builtin_amdgcn_mfma_f32_16x16x32_f16(af, pf[kt], az, 0, 0, 0);
        }
#pragma unroll
        for (int q = 0; q < 4; ++q) {
            int row = row0 + g * 4 + q;
            if (r < 2)      z12[row * 2 + r]       = az[q];
            else if (r < 4) z34[row * 2 + (r - 2)] = az[q];
        }
    }
}

// ---- edge-parallel pool: pool[g] += z12[src]*invdeg[dst]; + node z34 pass --
__global__ __launch_bounds__(256) void zpool_edge(
        const float2* __restrict__ z12, const float2* __restrict__ z34,
        const int* __restrict__ src, const int* __restrict__ dst,
        const int2* __restrict__ info, int E, float* __restrict__ pool) {
    __shared__ float lp[NGRAPHS * 2];
    int t = threadIdx.x;
    lp[t] = 0.f;
    __syncthreads();
    int tid = blockIdx.x * blockDim.x + t;
    int stride = gridDim.x * blockDim.x;
    for (int e = tid; e < E; e += stride) {
        int s = src[e], d = dst[e];
        float2 z = z12[s];
        int2 nf = info[d];
        float w = __int_as_float(nf.y);
        atomicAdd(&lp[nf.x * 2 + 0], z.x * w);
        atomicAdd(&lp[nf.x * 2 + 1], z.y * w);
    }
    for (int i = tid; i < NNODES; i += stride) {
        float2 zi = z34[i];
        int g = info[i].x;
        atomicAdd(&lp[g * 2 + 0], zi.x);
        atomicAdd(&lp[g * 2 + 1], zi.y);
    }
    __syncthreads();
    float v = lp[t];
    if (v != 0.f) atomicAdd(&pool[t], v);
}

__global__ void out_kernel(const float* __restrict__ pool, const int* __restrict__ batch,
                           const float* __restrict__ bo, float* __restrict__ out) {
    int t = threadIdx.x;              // 256 = 128 graphs x 2 classes
    int g = t >> 1, j = t & 1;
    int start = lower_bound(batch, NNODES, g);
    int end   = lower_bound(batch, NNODES, g + 1);
    int c = end - start;
    out[t] = (c > 0) ? pool[t] / (float)c + bo[j] : 0.f;
}

// ---- launch ---------------------------------------------------------------

extern "C" void kernel_launch(void* const* d_in, const int* in_sizes, int n_in,
                              void* d_out, int out_size, void* d_ws, size_t ws_size,
                              hipStream_t stream) {
    const float* x    = (const float*)d_in[0];
    const int*   eidx = (const int*)d_in[1];
    const int*   batch= (const int*)d_in[2];
    const float* Wl   = (const float*)d_in[3];
    const float* Wr   = (const float*)d_in[4];
    const float* b    = (const float*)d_in[5];
    const float* Wlo  = (const float*)d_in[6];
    const float* Wro  = (const float*)d_in[7];
    const float* bo   = (const float*)d_in[8];

    int E = in_sizes[1] / 2;
    const int* src = eidx;
    const int* dst = eidx + E;

    char* ws = (char*)d_ws;
    size_t hb = (size_t)NNODES * D * 2;       // fp16 h buffer = 8,192,000 B
    _Float16* xh   = (_Float16*)ws;
    _Float16* bufA = (_Float16*)(ws + hb);
    char* p = ws + 2 * hb;
    _Float16* Wlh  = (_Float16*)p;  p += 3 * D * D * 2;
    _Float16* Wrh  = (_Float16*)p;  p += 3 * D * D * 2;
    int*    col  = (int*)p;     p += (size_t)E * 4;
    int*    offs = (int*)p;     p += ((size_t)(NNODES + 1) * 4 + 15) / 16 * 16;
    int*    cur  = (int*)p;     p += (size_t)NNODES * 4;
    int*    cnt  = (int*)p;     p += (size_t)NNODES * 4;
    int*    bsum = (int*)p;     p += 1024;
    int2*   info = (int2*)p;    p += (size_t)NNODES * 8;
    float*  z12  = (float*)p;   p += (size_t)NNODES * 8;
    float*  z34  = (float*)p;   p += (size_t)NNODES * 8;
    float*  pool = (float*)p;

    const int NB = NNODES / 256;     // 250

    hipMemsetAsync(cnt, 0, (size_t)NNODES * 4, stream);
    hipMemsetAsync(pool, 0, NGRAPHS * 2 * sizeof(float), stream);

    tohalf_kernel<<<2000, 256, 0, stream>>>((const float4*)x, (half8*)xh, NNODES * D / 8,
                                            Wl, Wr, Wlh, Wrh);

    degree_kernel<<<1024, 256, 0, stream>>>(dst, E, cnt);
    blocksum_kernel<<<NB, 256, 0, stream>>>(cnt, bsum);
    scansmall_kernel<<<1, 256, 0, stream>>>(bsum, NB);
    scanfinal_kernel<<<NB, 256, 0, stream>>>(cnt, bsum, batch, offs, cur, info, NNODES);
    fill_xcd<<<1024, 256, 0, stream>>>(src, dst, cur, col, E);

    // L1: xh -> bufA ; L2: bufA -> xh ; L3: xh -> z12/z34 (no h3 materialized)
    layer_fused<0><<<1000, 256, 0, stream>>>(xh,   bufA, offs, col,
                                             Wlh,             Wrh,             b,
                                             nullptr, nullptr, nullptr, nullptr);
    layer_fused<0><<<1000, 256, 0, stream>>>(bufA, xh,   offs, col,
                                             Wlh + D * D,     Wrh + D * D,     b + D,
                                             nullptr, nullptr, nullptr, nullptr);
    layer_fused<1><<<1000, 256, 0, stream>>>(xh,   bufA, offs, col,
                                             Wlh + 2 * D * D, Wrh + 2 * D * D, b + 2 * D,
                                             Wlo, Wro, z12, z34);

    zpool_edge<<<1024, 256, 0, stream>>>((const float2*)z12, (const float2*)z34,
                                         src, dst, info, E, pool);
    out_kernel<<<1, 256, 0, stream>>>(pool, batch, bo, (float*)d_out);
}

// Round 7
// 245.121 us; speedup vs baseline: 5.4871x; 1.0080x over previous
//
#include <hip/hip_runtime.h>

#define NNODES 64000
#define NGRAPHS 128
#define D 64
#define NXCD 8

typedef _Float16 half8 __attribute__((ext_vector_type(8)));
typedef float f32x4 __attribute__((ext_vector_type(4)));

__device__ __forceinline__ int lower_bound(const int* __restrict__ a, int n, int key) {
    int lo = 0, hi = n;
    while (lo < hi) {
        int mid = (lo + hi) >> 1;
        if (a[mid] < key) lo = mid + 1; else hi = mid;
    }
    return lo;
}

// ---- conversions -----------------------------------------------------------

__global__ void tohalf_kernel(const float4* __restrict__ x, half8* __restrict__ xh, int n8,
                              const float* __restrict__ Wl, const float* __restrict__ Wr,
                              _Float16* __restrict__ Wlh, _Float16* __restrict__ Wrh) {
    int i = blockIdx.x * blockDim.x + threadIdx.x;
    int st = gridDim.x * blockDim.x;
    for (; i < n8; i += st) {
        float4 a = x[2 * i], b = x[2 * i + 1];
        half8 o;
        o[0] = (_Float16)a.x; o[1] = (_Float16)a.y; o[2] = (_Float16)a.z; o[3] = (_Float16)a.w;
        o[4] = (_Float16)b.x; o[5] = (_Float16)b.y; o[6] = (_Float16)b.z; o[7] = (_Float16)b.w;
        xh[i] = o;
    }
    int j = blockIdx.x * blockDim.x + threadIdx.x;
    if (j < 3 * D * D) {
        Wlh[j] = (_Float16)Wl[j];
        Wrh[j] = (_Float16)Wr[j];
    }
}

// ---- CSR build -------------------------------------------------------------

__global__ void degree_kernel(const int* __restrict__ dst, int E, int* __restrict__ cnt) {
    int i = blockIdx.x * blockDim.x + threadIdx.x;
    int stride = gridDim.x * blockDim.x;
    for (int e = i; e < E; e += stride) {
        int d = __builtin_nontemporal_load(dst + e);   // stream: don't evict cnt
        atomicAdd(&cnt[d], 1);
    }
}

__global__ void blocksum_kernel(const int* __restrict__ cnt, int* __restrict__ bsum) {
    __shared__ int s[256];
    int t = threadIdx.x;
    s[t] = cnt[blockIdx.x * 256 + t];
    __syncthreads();
    for (int off = 128; off > 0; off >>= 1) {
        if (t < off) s[t] += s[t + off];
        __syncthreads();
    }
    if (t == 0) bsum[blockIdx.x] = s[0];
}

__global__ void scansmall_kernel(int* __restrict__ bsum, int nb) {
    __shared__ int s[256];
    int t = threadIdx.x;
    int v = (t < nb) ? bsum[t] : 0;
    s[t] = v;
    __syncthreads();
    for (int off = 1; off < 256; off <<= 1) {
        int x = (t >= off) ? s[t - off] : 0;
        __syncthreads();
        s[t] += x;
        __syncthreads();
    }
    if (t < nb) bsum[t] = s[t] - v;   // exclusive
}

// per-block scan + base -> offs/cur; also packs info[i] = {batch[i], invdeg}
__global__ void scanfinal_kernel(const int* __restrict__ cnt, const int* __restrict__ bsum,
                                 const int* __restrict__ batch,
                                 int* __restrict__ offs, int* __restrict__ cur,
                                 int2* __restrict__ info, int N) {
    __shared__ int s[256];
    int t = threadIdx.x;
    int i = blockIdx.x * 256 + t;
    int v = cnt[i];
    s[t] = v;
    __syncthreads();
    for (int off = 1; off < 256; off <<= 1) {
        int x = (t >= off) ? s[t - off] : 0;
        __syncthreads();
        s[t] += x;
        __syncthreads();
    }
    int incl = s[t];
    int base = bsum[blockIdx.x];
    int o = base + incl - v;
    offs[i] = o;
    cur[i] = o;
    float inv = (v > 0) ? 1.f / (float)v : 0.f;
    info[i] = make_int2(batch[i], __float_as_int(inv));
    if (i == N - 1) offs[N] = base + incl;
}

// XCD-local fill: team (blockIdx%8) claims only dst in its 8000-node range, so
// each col/cur cache line is dirtied by a single XCD. Edge stream read with
// non-temporal loads so the 8 MB/team stream doesn't evict partial col lines.
__global__ void fill_xcd(const int* __restrict__ src, const int* __restrict__ dst,
                         int* __restrict__ cur, int* __restrict__ col, int E) {
    int team = blockIdx.x & (NXCD - 1);
    int sub  = blockIdx.x >> 3;
    int nsub = gridDim.x >> 3;
    int lo = team * (NNODES / NXCD), hi = lo + NNODES / NXCD;
    for (int e = sub * 256 + threadIdx.x; e < E; e += nsub * 256) {
        int d = __builtin_nontemporal_load(dst + e);
        if (d >= lo && d < hi) {
            int s = __builtin_nontemporal_load(src + e);
            int p = atomicAdd(&cur[d], 1);
            col[p] = s;
        }
    }
}

// ---- fused layer: gather-mean -> LDS tile -> MFMA transform (+optional proj)
// block = 4 waves; wave owns 16 consecutive nodes (one MFMA row-tile).
// PRJ: layer-3 variant — skip out write, emit z12/z34 = h3 @ Wlo^T / Wro^T.
template <int PRJ>
__global__ __launch_bounds__(256) void layer_fused(
        const _Float16* __restrict__ h, _Float16* __restrict__ out,
        const int* __restrict__ offs, const int* __restrict__ col,
        const _Float16* __restrict__ Wlh, const _Float16* __restrict__ Wrh,
        const float* __restrict__ b,
        const float* __restrict__ Wlo, const float* __restrict__ Wro,
        float* __restrict__ z12, float* __restrict__ z34) {
    __shared__ _Float16 tile[4][16][D];          // 8 KB: per-wave 16x64 staging
    int lane = threadIdx.x & 63;
    int w    = threadIdx.x >> 6;
    int row0 = (blockIdx.x * 4 + w) * 16;

    // phase A: aggregate 16 nodes (8 per pass); lane = (node-slot, 8-feat chunk)
    int ns = lane >> 3;
    int ch = lane & 7;
#pragma unroll
    for (int pass = 0; pass < 2; ++pass) {
        int i = row0 + pass * 8 + ns;
        int beg = offs[i], end = offs[i + 1];
        float s[8] = {0.f, 0.f, 0.f, 0.f, 0.f, 0.f, 0.f, 0.f};
        int e = beg;
        for (; e + 8 <= end; e += 8) {     // 8 independent row loads in flight
            int c[8];
#pragma unroll
            for (int u = 0; u < 8; ++u) c[u] = col[e + u];
            half8 v[8];
#pragma unroll
            for (int u = 0; u < 8; ++u)
                v[u] = *(const half8*)(h + (size_t)c[u] * D + ch * 8);
#pragma unroll
            for (int u = 0; u < 8; ++u)
#pragma unroll
                for (int j = 0; j < 8; ++j) s[j] += (float)v[u][j];
        }
        for (; e + 4 <= end; e += 4) {
            int c0 = col[e], c1 = col[e + 1], c2 = col[e + 2], c3 = col[e + 3];
            half8 v0 = *(const half8*)(h + (size_t)c0 * D + ch * 8);
            half8 v1 = *(const half8*)(h + (size_t)c1 * D + ch * 8);
            half8 v2 = *(const half8*)(h + (size_t)c2 * D + ch * 8);
            half8 v3 = *(const half8*)(h + (size_t)c3 * D + ch * 8);
#pragma unroll
            for (int j = 0; j < 8; ++j)
                s[j] += ((float)v0[j] + (float)v1[j]) + ((float)v2[j] + (float)v3[j]);
        }
        for (; e < end; ++e) {
            half8 v = *(const half8*)(h + (size_t)col[e] * D + ch * 8);
#pragma unroll
            for (int j = 0; j < 8; ++j) s[j] += (float)v[j];
        }
        float inv = (end > beg) ? 1.f / (float)(end - beg) : 0.f;
        half8 o;
#pragma unroll
        for (int j = 0; j < 8; ++j) o[j] = (_Float16)(s[j] * inv);
        *(half8*)(&tile[w][pass * 8 + ns][ch * 8]) = o;
    }
    // wave-private tile; DS ops complete in issue order per wave -> no barrier.

    int r = lane & 15;        // A-row / B-col / C-col
    int g = lane >> 4;        // k-subgroup

    // B fragments: [Wl;Wr] rows, K=128 split in 4 chunks of 32
    half8 bf[4][4];
#pragma unroll
    for (int kt = 0; kt < 4; ++kt) {
        const _Float16* Wm = (kt < 2) ? Wlh : Wrh;
        int kk = (kt & 1) * 32 + g * 8;
#pragma unroll
        for (int nt = 0; nt < 4; ++nt)
            bf[kt][nt] = *(const half8*)(Wm + (size_t)(nt * 16 + r) * D + kk);
    }

    f32x4 acc[4];
#pragma unroll
    for (int nt = 0; nt < 4; ++nt) {
        float bv = b[nt * 16 + r];
        acc[nt] = (f32x4){bv, bv, bv, bv};
    }

#pragma unroll
    for (int kt = 0; kt < 4; ++kt) {
        int kk = (kt & 1) * 32 + g * 8;
        half8 af;
        if (kt < 2) af = *(const half8*)(&tile[w][r][kk]);                 // aggr
        else        af = *(const half8*)(h + (size_t)(row0 + r) * D + kk); // self
#pragma unroll
        for (int nt = 0; nt < 4; ++nt)
            acc[nt] = __builtin_amdgcn_mfma_f32_16x16x32_f16(af, bf[kt][nt], acc[nt], 0, 0, 0);
    }

    // epilogue. C/D: col = lane&15, row = (lane>>4)*4 + q  [m89-verified]
    if (!PRJ) {
#pragma unroll
        for (int nt = 0; nt < 4; ++nt)
#pragma unroll
            for (int q = 0; q < 4; ++q) {
                int row = row0 + g * 4 + q;
                out[(size_t)row * D + nt * 16 + r] = (_Float16)fmaxf(acc[nt][q], 0.f);
            }
    } else {
        // stage relu(out) tile back to LDS (wave-private, in-order DS)
#pragma unroll
        for (int nt = 0; nt < 4; ++nt)
#pragma unroll
            for (int q = 0; q < 4; ++q)
                tile[w][g * 4 + q][nt * 16 + r] = (_Float16)fmaxf(acc[nt][q], 0.f);

        // B-frag of P rows {Wlo0,Wlo1,Wro0,Wro1} in cols 0..3
        half8 pf[2];
#pragma unroll
        for (int kt = 0; kt < 2; ++kt) {
            half8 t = {0, 0, 0, 0, 0, 0, 0, 0};
            if (r < 4) {
                const float* Pr = (r < 2) ? (Wlo + r * D) : (Wro + (r - 2) * D);
                int kk = kt * 32 + g * 8;
#pragma unroll
                for (int j = 0; j < 8; ++j) t[j] = (_Float16)Pr[kk + j];
            }
            pf[kt] = t;
        }
        f32x4 az = (f32x4){0.f, 0.f, 0.f, 0.f};
#pragma unroll
        for (int kt = 0; kt < 2; ++kt) {
            half8 af = *(const half8*)(&tile[w][r][kt * 32 + g * 8]);
            az = __builtin_amdgcn_mfma_f32_16x16x32_f16(af, pf[kt], az, 0, 0, 0);
        }
#pragma unroll
        for (int q = 0; q < 4; ++q) {
            int row = row0 + g * 4 + q;
            if (r < 2)      z12[row * 2 + r]       = az[q];
            else if (r < 4) z34[row * 2 + (r - 2)] = az[q];
        }
    }
}

// ---- edge-parallel pool: pool[g] += z12[src]*invdeg[dst]; + node z34 pass --
__global__ __launch_bounds__(256) void zpool_edge(
        const float2* __restrict__ z12, const float2* __restrict__ z34,
        const int* __restrict__ src, const int* __restrict__ dst,
        const int2* __restrict__ info, int E, float* __restrict__ pool) {
    __shared__ float lp[NGRAPHS * 2];
    int t = threadIdx.x;
    lp[t] = 0.f;
    __syncthreads();
    int tid = blockIdx.x * blockDim.x + t;
    int stride = gridDim.x * blockDim.x;
    for (int e = tid; e < E; e += stride) {
        int s = __builtin_nontemporal_load(src + e);
        int d = __builtin_nontemporal_load(dst + e);
        float2 z = z12[s];
        int2 nf = info[d];
        float w = __int_as_float(nf.y);
        atomicAdd(&lp[nf.x * 2 + 0], z.x * w);
        atomicAdd(&lp[nf.x * 2 + 1], z.y * w);
    }
    for (int i = tid; i < NNODES; i += stride) {
        float2 zi = z34[i];
        int g = info[i].x;
        atomicAdd(&lp[g * 2 + 0], zi.x);
        atomicAdd(&lp[g * 2 + 1], zi.y);
    }
    __syncthreads();
    float v = lp[t];
    if (v != 0.f) atomicAdd(&pool[t], v);
}

__global__ void out_kernel(const float* __restrict__ pool, const int* __restrict__ batch,
                           const float* __restrict__ bo, float* __restrict__ out) {
    int t = threadIdx.x;              // 256 = 128 graphs x 2 classes
    int g = t >> 1, j = t & 1;
    int start = lower_bound(batch, NNODES, g);
    int end   = lower_bound(batch, NNODES, g + 1);
    int c = end - start;
    out[t] = (c > 0) ? pool[t] / (float)c + bo[j] : 0.f;
}

// ---- launch ---------------------------------------------------------------

extern "C" void kernel_launch(void* const* d_in, const int* in_sizes, int n_in,
                              void* d_out, int out_size, void* d_ws, size_t ws_size,
                              hipStream_t stream) {
    const float* x    = (const float*)d_in[0];
    const int*   eidx = (const int*)d_in[1];
    const int*   batch= (const int*)d_in[2];
    const float* Wl   = (const float*)d_in[3];
    const float* Wr   = (const float*)d_in[4];
    const float* b    = (const float*)d_in[5];
    const float* Wlo  = (const float*)d_in[6];
    const float* Wro  = (const float*)d_in[7];
    const float* bo   = (const float*)d_in[8];

    int E = in_sizes[1] / 2;
    const int* src = eidx;
    const int* dst = eidx + E;

    char* ws = (char*)d_ws;
    size_t hb = (size_t)NNODES * D * 2;       // fp16 h buffer = 8,192,000 B
    _Float16* xh   = (_Float16*)ws;
    _Float16* bufA = (_Float16*)(ws + hb);
    char* p = ws + 2 * hb;
    _Float16* Wlh  = (_Float16*)p;  p += 3 * D * D * 2;
    _Float16* Wrh  = (_Float16*)p;  p += 3 * D * D * 2;
    int*    col  = (int*)p;     p += (size_t)E * 4;
    int*    offs = (int*)p;     p += ((size_t)(NNODES + 1) * 4 + 15) / 16 * 16;
    int*    cur  = (int*)p;     p += (size_t)NNODES * 4;
    int*    cnt  = (int*)p;     p += (size_t)NNODES * 4;
    int*    bsum = (int*)p;     p += 1024;
    int2*   info = (int2*)p;    p += (size_t)NNODES * 8;
    float*  z12  = (float*)p;   p += (size_t)NNODES * 8;
    float*  z34  = (float*)p;   p += (size_t)NNODES * 8;
    float*  pool = (float*)p;

    const int NB = NNODES / 256;     // 250

    hipMemsetAsync(cnt, 0, (size_t)NNODES * 4, stream);
    hipMemsetAsync(pool, 0, NGRAPHS * 2 * sizeof(float), stream);

    tohalf_kernel<<<2000, 256, 0, stream>>>((const float4*)x, (half8*)xh, NNODES * D / 8,
                                            Wl, Wr, Wlh, Wrh);

    degree_kernel<<<1024, 256, 0, stream>>>(dst, E, cnt);
    blocksum_kernel<<<NB, 256, 0, stream>>>(cnt, bsum);
    scansmall_kernel<<<1, 256, 0, stream>>>(bsum, NB);
    scanfinal_kernel<<<NB, 256, 0, stream>>>(cnt, bsum, batch, offs, cur, info, NNODES);
    fill_xcd<<<1024, 256, 0, stream>>>(src, dst, cur, col, E);

    // L1: xh -> bufA ; L2: bufA -> xh ; L3: xh -> z12/z34 (no h3 materialized)
    layer_fused<0><<<1000, 256, 0, stream>>>(xh,   bufA, offs, col,
                                             Wlh,             Wrh,             b,
                                             nullptr, nullptr, nullptr, nullptr);
    layer_fused<0><<<1000, 256, 0, stream>>>(bufA, xh,   offs, col,
                                             Wlh + D * D,     Wrh + D * D,     b + D,
                                             nullptr, nullptr, nullptr, nullptr);
    layer_fused<1><<<1000, 256, 0, stream>>>(xh,   bufA, offs, col,
                                             Wlh + 2 * D * D, Wrh + 2 * D * D, b + 2 * D,
                                             Wlo, Wro, z12, z34);

    zpool_edge<<<1024, 256, 0, stream>>>((const float2*)z12, (const float2*)z34,
                                         src, dst, info, E, pool);
    out_kernel<<<1, 256, 0, stream>>>(pool, batch, bo, (float*)d_out);
}